// Round 4
// baseline (943.322 us; speedup 1.0000x reference)
//
#include <hip/hip_runtime.h>
#include <math.h>

#define E 16
#define D 64
#define H 128
#define R 4            // n-rows per block
#define ROWS (R * E)   // 64 expert-rows per block (== 64 lanes)
#define PAD 130        // LDS row stride (floats): (2l+k)%32 -> conflict-light, 8B-aligned

// ---------------------------------------------------------------------------
// Prep: Wabc[c][j] = Wa + Wb + Wc  (spec_W1 rows 0..127, 128..255, 256..383)
// ---------------------------------------------------------------------------
__global__ void wabc_prep(const float* __restrict__ specW1, float* __restrict__ wabc) {
    int i = blockIdx.x * blockDim.x + threadIdx.x;
    if (i < H * H) {
        wabc[i] = specW1[i] + specW1[H * H + i] + specW1[2 * H * H + i];
    }
}

// ---------------------------------------------------------------------------
// Fused router, scalar-weight GEMM form. Block = 256 threads (4 waves), R=4.
// GEMM stages: lane l owns expert-row l; wave wq owns j-columns [wq*32,+32).
// Activations: per-lane LDS/global reads (1 read per 2 k, reused for 32 FMAs).
// Weights: wave-uniform addresses -> s_load into SGPRs, FMA with SGPR src.
// This cuts LDS traffic ~16x vs the broadcast-read form (the R0-R2 wall).
// ---------------------------------------------------------------------------
template <bool USE_WABC>
__global__ __launch_bounds__(256, 2)
void router_kernel(const float* __restrict__ tokens,
                   const float* __restrict__ encW1, const float* __restrict__ encB1,
                   const float* __restrict__ encW2, const float* __restrict__ encB2,
                   const float* __restrict__ specW1, const float* __restrict__ specB1,
                   const float* __restrict__ specW2,
                   const float* __restrict__ defW1, const float* __restrict__ defB1,
                   const float* __restrict__ defW2, const float* __restrict__ defB2,
                   const int* __restrict__ fiPtr, const int* __restrict__ tkPtr,
                   const float* __restrict__ wabc,
                   float* __restrict__ out, int N) {
    __shared__ float bufH[ROWS * PAD];   // 33.3 KB: enc1 h; dead after enc2 -> aliased for GEMV partials
    __shared__ float bufE[ROWS * PAD];   // 33.3 KB: encoded
    __shared__ float s_full[R * H];      // 2 KB
    __shared__ float s_glob[R * H];      // 2 KB
    __shared__ float s_mabs[R * H];      // 2 KB
    __shared__ float s_bias[R * H];      // 2 KB
    __shared__ float s_lp[4 * ROWS];     // 1 KB logit partials [wq][l]
    __shared__ float s_dred[R];

    const int tid  = threadIdx.x;
    const int lane = tid & 63;
    const int wq   = tid >> 6;
    const int jb   = __builtin_amdgcn_readfirstlane(wq) * 32;  // uniform j-base
    const int n0   = blockIdx.x * R;
    const int fi   = fiPtr[0];
    const int l    = lane;               // expert-row owned by this lane

    int tokRow = n0 * E + l;
    if (tokRow >= N * E) tokRow = 0;     // clamp (garbage rows never stored)
    const float* tokRowPtr = tokens + (size_t)tokRow * D;

    float acc[32];

    // ---- enc1: h = relu(tok @ W1 + b1), K=64 (A from global, L1-resident) ----
#pragma unroll
    for (int j = 0; j < 32; j++) acc[j] = 0.f;
    for (int k = 0; k < D; k += 2) {
        float2 a2 = *(const float2*)(tokRowPtr + k);
        const float* __restrict__ w0 = encW1 + k * H + jb;
        const float* __restrict__ w1 = encW1 + (k + 1) * H + jb;
#pragma unroll
        for (int j = 0; j < 32; j++) {
            acc[j] = fmaf(a2.x, w0[j], acc[j]);
            acc[j] = fmaf(a2.y, w1[j], acc[j]);
        }
    }
    {
        const float* __restrict__ b = encB1 + jb;
#pragma unroll
        for (int t = 0; t < 16; t++) {
            float2 o;
            o.x = fmaxf(acc[2 * t] + b[2 * t], 0.f);
            o.y = fmaxf(acc[2 * t + 1] + b[2 * t + 1], 0.f);
            *(float2*)(bufH + l * PAD + jb + 2 * t) = o;
        }
    }
    __syncthreads();

    // ---- enc2: encoded = relu(h @ W2 + b2), K=128 ----
#pragma unroll
    for (int j = 0; j < 32; j++) acc[j] = 0.f;
    for (int k = 0; k < H; k += 2) {
        float2 a2 = *(const float2*)(bufH + l * PAD + k);
        const float* __restrict__ w0 = encW2 + k * H + jb;
        const float* __restrict__ w1 = encW2 + (k + 1) * H + jb;
#pragma unroll
        for (int j = 0; j < 32; j++) {
            acc[j] = fmaf(a2.x, w0[j], acc[j]);
            acc[j] = fmaf(a2.y, w1[j], acc[j]);
        }
    }
    {
        const float* __restrict__ b = encB2 + jb;
#pragma unroll
        for (int t = 0; t < 16; t++) {
            float2 o;
            o.x = fmaxf(acc[2 * t] + b[2 * t], 0.f);
            o.y = fmaxf(acc[2 * t + 1] + b[2 * t + 1], 0.f);
            *(float2*)(bufE + l * PAD + jb + 2 * t) = o;
        }
    }
    __syncthreads();

    // ---- stats: full, glob mean, mean|delta| per (r, c). No absdelta store. ----
    {
        const int r  = tid >> 6;     // 0..3
        const int cb = tid & 63;
#pragma unroll
        for (int half = 0; half < 2; half++) {
            const int c = cb + half * 64;
            const float* er = bufE + (r * E) * PAD + c;
            float v[E];
#pragma unroll
            for (int e = 0; e < E; e++) v[e] = er[e * PAD];
            float s = 0.f;
#pragma unroll
            for (int e = 0; e < E; e++) s += v[e];
            float fc = v[fi];
            float ma = 0.f;
#pragma unroll
            for (int e = 0; e < E; e++) ma += fabsf(v[e] - fc);
            s_full[r * H + c] = fc;
            s_glob[r * H + c] = s * (1.f / 16.f);
            s_mabs[r * H + c] = ma * (1.f / 16.f);
        }
    }
    __syncthreads();

    // ---- GEMV partials (bias = full@Wb + glob@Wc; def head), into dead bufH ----
    float* s_pB = bufH;              // 2*R*H = 1024 floats
    float* s_pD = bufH + 2 * R * H;  // 1024 floats
    {
        const int jp = tid & 63;
        const int jj = jp * 2;
        const int kh = (tid >> 6) & 1;  // K-half
        const int rg = tid >> 7;        // r-group
        const int c0 = kh * 64;
        const float* __restrict__ Wb = specW1 + H * H;
        const float* __restrict__ Wc = specW1 + 2 * H * H;
        float accB[2][2] = {{0.f, 0.f}, {0.f, 0.f}};
        float accD[2][2] = {{0.f, 0.f}, {0.f, 0.f}};
        for (int cc = 0; cc < 64; cc++) {
            const int c = c0 + cc;
            float2 wb = *(const float2*)(Wb + c * H + jj);
            float2 wc = *(const float2*)(Wc + c * H + jj);
            float2 d0 = *(const float2*)(defW1 + c * H + jj);
            float2 d1 = *(const float2*)(defW1 + (H + c) * H + jj);
            float2 d2 = *(const float2*)(defW1 + (2 * H + c) * H + jj);
#pragma unroll
            for (int rl = 0; rl < 2; rl++) {
                const int r = rg * 2 + rl;
                float fv = s_full[r * H + c];
                float gv = s_glob[r * H + c];
                float mv = s_mabs[r * H + c];
                accB[rl][0] = fmaf(fv, wb.x, accB[rl][0]);
                accB[rl][1] = fmaf(fv, wb.y, accB[rl][1]);
                accB[rl][0] = fmaf(gv, wc.x, accB[rl][0]);
                accB[rl][1] = fmaf(gv, wc.y, accB[rl][1]);
                accD[rl][0] = fmaf(fv, d0.x, accD[rl][0]);
                accD[rl][1] = fmaf(fv, d0.y, accD[rl][1]);
                accD[rl][0] = fmaf(gv, d1.x, accD[rl][0]);
                accD[rl][1] = fmaf(gv, d1.y, accD[rl][1]);
                accD[rl][0] = fmaf(mv, d2.x, accD[rl][0]);
                accD[rl][1] = fmaf(mv, d2.y, accD[rl][1]);
            }
        }
#pragma unroll
        for (int rl = 0; rl < 2; rl++) {
            const int r = rg * 2 + rl;
            *(float2*)(s_pB + (kh * R + r) * H + jj) = make_float2(accB[rl][0], accB[rl][1]);
            *(float2*)(s_pD + (kh * R + r) * H + jj) = make_float2(accD[rl][0], accD[rl][1]);
        }
    }
    __syncthreads();

    // ---- finalize bias + defer logit (wave wq owns n-row wq) ----
    {
        float dv = 0.f;
#pragma unroll
        for (int t = 0; t < 2; t++) {
            const int j = lane + t * 64;
            float pb = s_pB[wq * H + j] + s_pB[(R + wq) * H + j];
            s_bias[wq * H + j] = specB1[j] - pb;
            float pd = defB1[j] + s_pD[wq * H + j] + s_pD[(R + wq) * H + j];
            dv += fmaxf(pd, 0.f) * defW2[j];
        }
#pragma unroll
        for (int off = 32; off; off >>= 1) dv += __shfl_xor(dv, off, 64);
        if (lane == 0) s_dred[wq] = dv;
    }
    __syncthreads();

    // ---- spec GEMM: relu(enc@Wabc + |enc-full|@Wd + bias) -> logit partials ----
#pragma unroll
    for (int j = 0; j < 32; j++) acc[j] = 0.f;
    {
        const int rr = l >> 4;
        const float* __restrict__ Wd = specW1 + 3 * H * H;
        for (int k = 0; k < H; k += 2) {
            float2 e2 = *(const float2*)(bufE + l * PAD + k);
            float2 f2 = *(const float2*)(s_full + rr * H + k);
            float a0 = fabsf(e2.x - f2.x);
            float a1 = fabsf(e2.y - f2.y);
            const float* __restrict__ wd0 = Wd + k * H + jb;
            const float* __restrict__ wd1 = Wd + (k + 1) * H + jb;
            if (USE_WABC) {
                const float* __restrict__ wa0 = wabc + k * H + jb;
                const float* __restrict__ wa1 = wabc + (k + 1) * H + jb;
#pragma unroll
                for (int j = 0; j < 32; j++) {
                    acc[j] = fmaf(e2.x, wa0[j], acc[j]);
                    acc[j] = fmaf(e2.y, wa1[j], acc[j]);
                    acc[j] = fmaf(a0, wd0[j], acc[j]);
                    acc[j] = fmaf(a1, wd1[j], acc[j]);
                }
            } else {
                const float* __restrict__ p0 = specW1 + k * H + jb;
                const float* __restrict__ p1 = specW1 + (k + 1) * H + jb;
#pragma unroll
                for (int j = 0; j < 32; j++) {
                    float w_a0 = p0[j] + p0[H * H + j] + p0[2 * H * H + j];
                    float w_a1 = p1[j] + p1[H * H + j] + p1[2 * H * H + j];
                    acc[j] = fmaf(e2.x, w_a0, acc[j]);
                    acc[j] = fmaf(e2.y, w_a1, acc[j]);
                    acc[j] = fmaf(a0, wd0[j], acc[j]);
                    acc[j] = fmaf(a1, wd1[j], acc[j]);
                }
            }
        }
        // logit partial over this wave's j-chunk (spec_b2 dropped: shift-invariant)
        float p = 0.f;
        const float* __restrict__ w2 = specW2 + jb;
#pragma unroll
        for (int j = 0; j < 32; j++) {
            float b = s_bias[rr * H + jb + j];
            p += fmaxf(acc[j] + b, 0.f) * w2[j];
        }
        s_lp[wq * ROWS + l] = p;
    }
    __syncthreads();

    // ---- finalize (R threads: one per n-row) ----
    if (tid < R && (n0 + tid) < N) {
        const int r = tid;
        const int n = n0 + r;
        float s = s_dred[r] + defB2[0];
        out[(size_t)N * E + n] = 1.f / (1.f + expf(-s));
        float lg[E];
#pragma unroll
        for (int e = 0; e < E; e++)
            lg[e] = s_lp[0 * ROWS + r * E + e] + s_lp[1 * ROWS + r * E + e]
                  + s_lp[2 * ROWS + r * E + e] + s_lp[3 * ROWS + r * E + e];
        int k = tkPtr[0];
        if (k < 1) k = 1;
        if (k > E - 1) k = E - 1;
        unsigned chosen = 0u;
        for (int kk = 0; kk < k; kk++) {
            float bv = -INFINITY;
            int bi = 0;
            for (int e = 0; e < E; e++) {
                if (e == fi || ((chosen >> e) & 1u)) continue;
                float v = lg[e];
                if (v > bv) { bv = v; bi = e; }
            }
            chosen |= (1u << bi);
        }
        float mx = -INFINITY;
        for (int e = 0; e < E; e++)
            if ((chosen >> e) & 1u) { float v = lg[e]; if (v > mx) mx = v; }
        float ssum = 0.f;
        for (int e = 0; e < E; e++)
            if ((chosen >> e) & 1u) ssum += expf(lg[e] - mx);
        float inv = 1.f / ssum;
        for (int e = 0; e < E; e++) {
            float wv = 0.f;
            if ((chosen >> e) & 1u) wv = expf(lg[e] - mx) * inv;
            out[(size_t)n * E + e] = wv;
        }
    }
}

extern "C" void kernel_launch(void* const* d_in, const int* in_sizes, int n_in,
                              void* d_out, int out_size, void* d_ws, size_t ws_size,
                              hipStream_t stream) {
    (void)n_in; (void)out_size;
    const float* tokens = (const float*)d_in[0];
    const float* encW1  = (const float*)d_in[1];
    const float* encB1  = (const float*)d_in[2];
    const float* encW2  = (const float*)d_in[3];
    const float* encB2  = (const float*)d_in[4];
    const float* specW1 = (const float*)d_in[5];
    const float* specB1 = (const float*)d_in[6];
    const float* specW2 = (const float*)d_in[7];
    // d_in[8] = spec_b2 (unused: softmax is shift-invariant)
    const float* defW1  = (const float*)d_in[9];
    const float* defB1  = (const float*)d_in[10];
    const float* defW2  = (const float*)d_in[11];
    const float* defB2  = (const float*)d_in[12];
    const int*   fiPtr  = (const int*)d_in[13];
    const int*   tkPtr  = (const int*)d_in[14];
    float* out = (float*)d_out;

    const int N = in_sizes[0] / (E * D);
    const int grid = (N + R - 1) / R;
    const bool useWs = (d_ws != nullptr) && (ws_size >= (size_t)(H * H * sizeof(float)));

    if (useWs) {
        wabc_prep<<<(H * H + 255) / 256, 256, 0, stream>>>(specW1, (float*)d_ws);
        router_kernel<true><<<grid, 256, 0, stream>>>(
            tokens, encW1, encB1, encW2, encB2, specW1, specB1, specW2,
            defW1, defB1, defW2, defB2, fiPtr, tkPtr, (const float*)d_ws, out, N);
    } else {
        router_kernel<false><<<grid, 256, 0, stream>>>(
            tokens, encW1, encB1, encW2, encB2, specW1, specB1, specW2,
            defW1, defB1, defW2, defB2, fiPtr, tkPtr, nullptr, out, N);
    }
}

// Round 5
// 843.693 us; speedup vs baseline: 1.1181x; 1.1181x over previous
//
#include <hip/hip_runtime.h>
#include <math.h>

#define E 16
#define D 64
#define H 128
#define R 4            // n-rows per block
#define ROWS (R * E)   // 64 expert-rows per block
#define SP 132         // LDS row stride (floats): quarters land 16 banks apart -> 2-way (free)

// ---------------------------------------------------------------------------
// Prep: Wabc[c][j] = Wa + Wb + Wc  (spec_W1 rows 0..127, 128..255, 256..383)
// ---------------------------------------------------------------------------
__global__ void wabc_prep(const float* __restrict__ specW1, float* __restrict__ wabc) {
    int i = blockIdx.x * blockDim.x + threadIdx.x;
    if (i < H * H) {
        wabc[i] = specW1[i] + specW1[H * H + i] + specW1[2 * H * H + i];
    }
}

// ---------------------------------------------------------------------------
// Fused router. Block = 256 threads (4 waves), R=4 rows/block. Wave wq owns
// n-row wq (16 expert-rows x all 128 cols). Lane = (mq = lane>>4, jq = lane&15):
// acc[4][8] = rows {wq*16+4mq..+3} x cols {jq*8..+7}. Per 128 FMA-instrs:
// 4 ds_read_b128 (4 distinct rows, 2-way banks = free) + 8 dwordx4 weight
// loads -- 4x denser than the R2 broadcast form, conflict-light unlike R3.
// ---------------------------------------------------------------------------
template <bool USE_WABC>
__global__ __launch_bounds__(256, 2)
void router_kernel(const float* __restrict__ tokens,
                   const float* __restrict__ encW1, const float* __restrict__ encB1,
                   const float* __restrict__ encW2, const float* __restrict__ encB2,
                   const float* __restrict__ specW1, const float* __restrict__ specB1,
                   const float* __restrict__ specW2,
                   const float* __restrict__ defW1, const float* __restrict__ defB1,
                   const float* __restrict__ defW2, const float* __restrict__ defB2,
                   const int* __restrict__ fiPtr, const int* __restrict__ tkPtr,
                   const float* __restrict__ wabc,
                   float* __restrict__ out, int N) {
    __shared__ float bufA[ROWS * SP];   // 33.8 KB: tokens -> encoded
    __shared__ float bufH[ROWS * SP];   // 33.8 KB: enc1 h -> GEMV partial scratch
    __shared__ float s_full[R * H];     // 2 KB
    __shared__ float s_glob[R * H];     // 2 KB
    __shared__ float s_mabs[R * H];     // 2 KB
    __shared__ float s_bias[R * H];     // 2 KB
    __shared__ float s_lg[ROWS];        // complete logits
    __shared__ float s_dred[R];

    const int tid  = threadIdx.x;
    const int lane = tid & 63;
    const int wq   = tid >> 6;         // wave == n-row in GEMM stages
    const int mq   = lane >> 4;        // row-quarter 0..3
    const int jq   = lane & 15;
    const int j0   = jq * 8;           // this lane's 8-col chunk
    const int n0   = blockIdx.x * R;
    const int fi   = fiPtr[0];
    const int gb   = wq * 16 + 4 * mq; // first of this lane's 4 expert-rows

    // ---- stage 1: tokens -> bufA (row-major, stride SP, cols 0..63) ----
    {
        const size_t base  = (size_t)n0 * (E * D);
        const size_t total = (size_t)N * (E * D);
#pragma unroll
        for (int it = 0; it < 4; it++) {
            int f   = tid + it * 256;          // float4 id (1024 total)
            int row = f >> 4;                  // 16 float4 per 64-float row
            int col = (f & 15) * 4;
            size_t off = base + (size_t)row * D + col;
            float4 v = make_float4(0.f, 0.f, 0.f, 0.f);
            if (off + 3 < total) v = *(const float4*)(tokens + off);
            *(float4*)(bufA + row * SP + col) = v;
        }
    }
    __syncthreads();

    // ---- enc1: h = relu(tok @ W1 + b1), K=64; bufA -> bufH ----
    {
        float acc[4][8];
#pragma unroll
        for (int i = 0; i < 4; i++)
#pragma unroll
            for (int j = 0; j < 8; j++) acc[i][j] = 0.f;
#pragma unroll 2
        for (int k = 0; k < D; k += 4) {
            float4 w[4][2];
#pragma unroll
            for (int kk = 0; kk < 4; kk++) {
                w[kk][0] = *(const float4*)(encW1 + (k + kk) * H + j0);
                w[kk][1] = *(const float4*)(encW1 + (k + kk) * H + j0 + 4);
            }
#pragma unroll
            for (int i = 0; i < 4; i++) {
                float4 a4 = *(const float4*)(bufA + (gb + i) * SP + k);
                const float av[4] = {a4.x, a4.y, a4.z, a4.w};
#pragma unroll
                for (int kk = 0; kk < 4; kk++) {
                    float a = av[kk];
                    acc[i][0] = fmaf(a, w[kk][0].x, acc[i][0]);
                    acc[i][1] = fmaf(a, w[kk][0].y, acc[i][1]);
                    acc[i][2] = fmaf(a, w[kk][0].z, acc[i][2]);
                    acc[i][3] = fmaf(a, w[kk][0].w, acc[i][3]);
                    acc[i][4] = fmaf(a, w[kk][1].x, acc[i][4]);
                    acc[i][5] = fmaf(a, w[kk][1].y, acc[i][5]);
                    acc[i][6] = fmaf(a, w[kk][1].z, acc[i][6]);
                    acc[i][7] = fmaf(a, w[kk][1].w, acc[i][7]);
                }
            }
        }
        float4 b0 = *(const float4*)(encB1 + j0);
        float4 b1 = *(const float4*)(encB1 + j0 + 4);
#pragma unroll
        for (int i = 0; i < 4; i++) {
            float4 o0, o1;
            o0.x = fmaxf(acc[i][0] + b0.x, 0.f);
            o0.y = fmaxf(acc[i][1] + b0.y, 0.f);
            o0.z = fmaxf(acc[i][2] + b0.z, 0.f);
            o0.w = fmaxf(acc[i][3] + b0.w, 0.f);
            o1.x = fmaxf(acc[i][4] + b1.x, 0.f);
            o1.y = fmaxf(acc[i][5] + b1.y, 0.f);
            o1.z = fmaxf(acc[i][6] + b1.z, 0.f);
            o1.w = fmaxf(acc[i][7] + b1.w, 0.f);
            *(float4*)(bufH + (gb + i) * SP + j0)     = o0;
            *(float4*)(bufH + (gb + i) * SP + j0 + 4) = o1;
        }
    }
    __syncthreads();

    // ---- enc2: encoded = relu(h @ W2 + b2), K=128; bufH -> bufA ----
    {
        float acc[4][8];
#pragma unroll
        for (int i = 0; i < 4; i++)
#pragma unroll
            for (int j = 0; j < 8; j++) acc[i][j] = 0.f;
#pragma unroll 2
        for (int k = 0; k < H; k += 4) {
            float4 w[4][2];
#pragma unroll
            for (int kk = 0; kk < 4; kk++) {
                w[kk][0] = *(const float4*)(encW2 + (k + kk) * H + j0);
                w[kk][1] = *(const float4*)(encW2 + (k + kk) * H + j0 + 4);
            }
#pragma unroll
            for (int i = 0; i < 4; i++) {
                float4 a4 = *(const float4*)(bufH + (gb + i) * SP + k);
                const float av[4] = {a4.x, a4.y, a4.z, a4.w};
#pragma unroll
                for (int kk = 0; kk < 4; kk++) {
                    float a = av[kk];
                    acc[i][0] = fmaf(a, w[kk][0].x, acc[i][0]);
                    acc[i][1] = fmaf(a, w[kk][0].y, acc[i][1]);
                    acc[i][2] = fmaf(a, w[kk][0].z, acc[i][2]);
                    acc[i][3] = fmaf(a, w[kk][0].w, acc[i][3]);
                    acc[i][4] = fmaf(a, w[kk][1].x, acc[i][4]);
                    acc[i][5] = fmaf(a, w[kk][1].y, acc[i][5]);
                    acc[i][6] = fmaf(a, w[kk][1].z, acc[i][6]);
                    acc[i][7] = fmaf(a, w[kk][1].w, acc[i][7]);
                }
            }
        }
        float4 b0 = *(const float4*)(encB2 + j0);
        float4 b1 = *(const float4*)(encB2 + j0 + 4);
#pragma unroll
        for (int i = 0; i < 4; i++) {
            float4 o0, o1;
            o0.x = fmaxf(acc[i][0] + b0.x, 0.f);
            o0.y = fmaxf(acc[i][1] + b0.y, 0.f);
            o0.z = fmaxf(acc[i][2] + b0.z, 0.f);
            o0.w = fmaxf(acc[i][3] + b0.w, 0.f);
            o1.x = fmaxf(acc[i][4] + b1.x, 0.f);
            o1.y = fmaxf(acc[i][5] + b1.y, 0.f);
            o1.z = fmaxf(acc[i][6] + b1.z, 0.f);
            o1.w = fmaxf(acc[i][7] + b1.w, 0.f);
            *(float4*)(bufA + (gb + i) * SP + j0)     = o0;
            *(float4*)(bufA + (gb + i) * SP + j0 + 4) = o1;
        }
    }
    __syncthreads();

    // ---- stats: full, glob mean, mean|delta| per (r=wq, c). ----
    {
#pragma unroll
        for (int half = 0; half < 2; half++) {
            const int c = lane + half * 64;
            const float* er = bufA + (wq * E) * SP + c;
            float v[E];
#pragma unroll
            for (int e = 0; e < E; e++) v[e] = er[e * SP];
            float s = 0.f;
#pragma unroll
            for (int e = 0; e < E; e++) s += v[e];
            float fc = v[fi];
            float ma = 0.f;
#pragma unroll
            for (int e = 0; e < E; e++) ma += fabsf(v[e] - fc);
            s_full[wq * H + c] = fc;
            s_glob[wq * H + c] = s * (1.f / 16.f);
            s_mabs[wq * H + c] = ma * (1.f / 16.f);
        }
    }
    __syncthreads();

    // ---- GEMV partials (bias = full@Wb + glob@Wc; def head), into dead bufH ----
    float* s_pB = bufH;              // 2*R*H = 1024 floats
    float* s_pD = bufH + 2 * R * H;  // 1024 floats
    {
        const int jp = tid & 63;
        const int jj = jp * 2;
        const int kh = (tid >> 6) & 1;  // K-half
        const int rg = tid >> 7;        // r-group
        const int c0 = kh * 64;
        const float* __restrict__ Wb = specW1 + H * H;
        const float* __restrict__ Wc = specW1 + 2 * H * H;
        float accB[2][2] = {{0.f, 0.f}, {0.f, 0.f}};
        float accD[2][2] = {{0.f, 0.f}, {0.f, 0.f}};
        for (int cc = 0; cc < 64; cc++) {
            const int c = c0 + cc;
            float2 wb = *(const float2*)(Wb + c * H + jj);
            float2 wc = *(const float2*)(Wc + c * H + jj);
            float2 d0 = *(const float2*)(defW1 + c * H + jj);
            float2 d1 = *(const float2*)(defW1 + (H + c) * H + jj);
            float2 d2 = *(const float2*)(defW1 + (2 * H + c) * H + jj);
#pragma unroll
            for (int rl = 0; rl < 2; rl++) {
                const int r = rg * 2 + rl;
                float fv = s_full[r * H + c];
                float gv = s_glob[r * H + c];
                float mv = s_mabs[r * H + c];
                accB[rl][0] = fmaf(fv, wb.x, accB[rl][0]);
                accB[rl][1] = fmaf(fv, wb.y, accB[rl][1]);
                accB[rl][0] = fmaf(gv, wc.x, accB[rl][0]);
                accB[rl][1] = fmaf(gv, wc.y, accB[rl][1]);
                accD[rl][0] = fmaf(fv, d0.x, accD[rl][0]);
                accD[rl][1] = fmaf(fv, d0.y, accD[rl][1]);
                accD[rl][0] = fmaf(gv, d1.x, accD[rl][0]);
                accD[rl][1] = fmaf(gv, d1.y, accD[rl][1]);
                accD[rl][0] = fmaf(mv, d2.x, accD[rl][0]);
                accD[rl][1] = fmaf(mv, d2.y, accD[rl][1]);
            }
        }
#pragma unroll
        for (int rl = 0; rl < 2; rl++) {
            const int r = rg * 2 + rl;
            *(float2*)(s_pB + (kh * R + r) * H + jj) = make_float2(accB[rl][0], accB[rl][1]);
            *(float2*)(s_pD + (kh * R + r) * H + jj) = make_float2(accD[rl][0], accD[rl][1]);
        }
    }
    __syncthreads();

    // ---- finalize bias + defer logit (wave wq owns n-row wq) ----
    {
        float dv = 0.f;
#pragma unroll
        for (int t = 0; t < 2; t++) {
            const int j = lane + t * 64;
            float pb = s_pB[wq * H + j] + s_pB[(R + wq) * H + j];
            s_bias[wq * H + j] = specB1[j] - pb;
            float pd = defB1[j] + s_pD[wq * H + j] + s_pD[(R + wq) * H + j];
            dv += fmaxf(pd, 0.f) * defW2[j];
        }
#pragma unroll
        for (int off = 32; off; off >>= 1) dv += __shfl_xor(dv, off, 64);
        if (lane == 0) s_dred[wq] = dv;
    }
    __syncthreads();

    // ---- spec GEMM: relu(enc@Wabc + |enc-full|@Wd + bias) -> logits ----
    {
        float acc[4][8];
#pragma unroll
        for (int i = 0; i < 4; i++)
#pragma unroll
            for (int j = 0; j < 8; j++) acc[i][j] = 0.f;
        const float* __restrict__ Wd = specW1 + 3 * H * H;
#pragma unroll 2
        for (int k = 0; k < H; k += 4) {
            float4 wa[4][2], wd[4][2];
#pragma unroll
            for (int kk = 0; kk < 4; kk++) {
                wd[kk][0] = *(const float4*)(Wd + (k + kk) * H + j0);
                wd[kk][1] = *(const float4*)(Wd + (k + kk) * H + j0 + 4);
                if (USE_WABC) {
                    wa[kk][0] = *(const float4*)(wabc + (k + kk) * H + j0);
                    wa[kk][1] = *(const float4*)(wabc + (k + kk) * H + j0 + 4);
                } else {
                    const float* p = specW1 + (k + kk) * H + j0;
                    float4 x0 = *(const float4*)(p);
                    float4 x1 = *(const float4*)(p + H * H);
                    float4 x2 = *(const float4*)(p + 2 * H * H);
                    wa[kk][0] = make_float4(x0.x + x1.x + x2.x, x0.y + x1.y + x2.y,
                                            x0.z + x1.z + x2.z, x0.w + x1.w + x2.w);
                    x0 = *(const float4*)(p + 4);
                    x1 = *(const float4*)(p + H * H + 4);
                    x2 = *(const float4*)(p + 2 * H * H + 4);
                    wa[kk][1] = make_float4(x0.x + x1.x + x2.x, x0.y + x1.y + x2.y,
                                            x0.z + x1.z + x2.z, x0.w + x1.w + x2.w);
                }
            }
            float4 f4 = *(const float4*)(s_full + wq * H + k);   // broadcast
            const float fv[4] = {f4.x, f4.y, f4.z, f4.w};
#pragma unroll
            for (int i = 0; i < 4; i++) {
                float4 e4 = *(const float4*)(bufA + (gb + i) * SP + k);
                const float ev[4] = {e4.x, e4.y, e4.z, e4.w};
#pragma unroll
                for (int kk = 0; kk < 4; kk++) {
                    float e = ev[kk];
                    float a = fabsf(e - fv[kk]);
                    acc[i][0] = fmaf(e, wa[kk][0].x, acc[i][0]);
                    acc[i][1] = fmaf(e, wa[kk][0].y, acc[i][1]);
                    acc[i][2] = fmaf(e, wa[kk][0].z, acc[i][2]);
                    acc[i][3] = fmaf(e, wa[kk][0].w, acc[i][3]);
                    acc[i][4] = fmaf(e, wa[kk][1].x, acc[i][4]);
                    acc[i][5] = fmaf(e, wa[kk][1].y, acc[i][5]);
                    acc[i][6] = fmaf(e, wa[kk][1].z, acc[i][6]);
                    acc[i][7] = fmaf(e, wa[kk][1].w, acc[i][7]);
                    acc[i][0] = fmaf(a, wd[kk][0].x, acc[i][0]);
                    acc[i][1] = fmaf(a, wd[kk][0].y, acc[i][1]);
                    acc[i][2] = fmaf(a, wd[kk][0].z, acc[i][2]);
                    acc[i][3] = fmaf(a, wd[kk][0].w, acc[i][3]);
                    acc[i][4] = fmaf(a, wd[kk][1].x, acc[i][4]);
                    acc[i][5] = fmaf(a, wd[kk][1].y, acc[i][5]);
                    acc[i][6] = fmaf(a, wd[kk][1].z, acc[i][6]);
                    acc[i][7] = fmaf(a, wd[kk][1].w, acc[i][7]);
                }
            }
        }
        // epilogue: complete logit per row via 16-lane reduce (spec_b2 dropped)
        float4 bb0 = *(const float4*)(s_bias + wq * H + j0);
        float4 bb1 = *(const float4*)(s_bias + wq * H + j0 + 4);
        float4 w20 = *(const float4*)(specW2 + j0);
        float4 w21 = *(const float4*)(specW2 + j0 + 4);
#pragma unroll
        for (int i = 0; i < 4; i++) {
            float p = 0.f;
            p += fmaxf(acc[i][0] + bb0.x, 0.f) * w20.x;
            p += fmaxf(acc[i][1] + bb0.y, 0.f) * w20.y;
            p += fmaxf(acc[i][2] + bb0.z, 0.f) * w20.z;
            p += fmaxf(acc[i][3] + bb0.w, 0.f) * w20.w;
            p += fmaxf(acc[i][4] + bb1.x, 0.f) * w21.x;
            p += fmaxf(acc[i][5] + bb1.y, 0.f) * w21.y;
            p += fmaxf(acc[i][6] + bb1.z, 0.f) * w21.z;
            p += fmaxf(acc[i][7] + bb1.w, 0.f) * w21.w;
#pragma unroll
            for (int off = 1; off < 16; off <<= 1) p += __shfl_xor(p, off, 64);
            if (jq == 0) s_lg[wq * E + 4 * mq + i] = p;
        }
    }
    __syncthreads();

    // ---- finalize (R threads: one per n-row) ----
    if (tid < R && (n0 + tid) < N) {
        const int r = tid;
        const int n = n0 + r;
        float s = s_dred[r] + defB2[0];
        out[(size_t)N * E + n] = 1.f / (1.f + expf(-s));
        float lg[E];
#pragma unroll
        for (int e = 0; e < E; e++) lg[e] = s_lg[r * E + e];
        int k = tkPtr[0];
        if (k < 1) k = 1;
        if (k > E - 1) k = E - 1;
        unsigned chosen = 0u;
        for (int kk = 0; kk < k; kk++) {
            float bv = -INFINITY;
            int bi = 0;
            for (int e = 0; e < E; e++) {
                if (e == fi || ((chosen >> e) & 1u)) continue;
                float v = lg[e];
                if (v > bv) { bv = v; bi = e; }
            }
            chosen |= (1u << bi);
        }
        float mx = -INFINITY;
        for (int e = 0; e < E; e++)
            if ((chosen >> e) & 1u) { float v = lg[e]; if (v > mx) mx = v; }
        float ssum = 0.f;
        for (int e = 0; e < E; e++)
            if ((chosen >> e) & 1u) ssum += expf(lg[e] - mx);
        float inv = 1.f / ssum;
        for (int e = 0; e < E; e++) {
            float wv = 0.f;
            if ((chosen >> e) & 1u) wv = expf(lg[e] - mx) * inv;
            out[(size_t)n * E + e] = wv;
        }
    }
}

extern "C" void kernel_launch(void* const* d_in, const int* in_sizes, int n_in,
                              void* d_out, int out_size, void* d_ws, size_t ws_size,
                              hipStream_t stream) {
    (void)n_in; (void)out_size;
    const float* tokens = (const float*)d_in[0];
    const float* encW1  = (const float*)d_in[1];
    const float* encB1  = (const float*)d_in[2];
    const float* encW2  = (const float*)d_in[3];
    const float* encB2  = (const float*)d_in[4];
    const float* specW1 = (const float*)d_in[5];
    const float* specB1 = (const float*)d_in[6];
    const float* specW2 = (const float*)d_in[7];
    // d_in[8] = spec_b2 (unused: softmax is shift-invariant)
    const float* defW1  = (const float*)d_in[9];
    const float* defB1  = (const float*)d_in[10];
    const float* defW2  = (const float*)d_in[11];
    const float* defB2  = (const float*)d_in[12];
    const int*   fiPtr  = (const int*)d_in[13];
    const int*   tkPtr  = (const int*)d_in[14];
    float* out = (float*)d_out;

    const int N = in_sizes[0] / (E * D);
    const int grid = (N + R - 1) / R;
    const bool useWs = (d_ws != nullptr) && (ws_size >= (size_t)(H * H * sizeof(float)));

    if (useWs) {
        wabc_prep<<<(H * H + 255) / 256, 256, 0, stream>>>(specW1, (float*)d_ws);
        router_kernel<true><<<grid, 256, 0, stream>>>(
            tokens, encW1, encB1, encW2, encB2, specW1, specB1, specW2,
            defW1, defB1, defW2, defB2, fiPtr, tkPtr, (const float*)d_ws, out, N);
    } else {
        router_kernel<false><<<grid, 256, 0, stream>>>(
            tokens, encW1, encB1, encW2, encB2, specW1, specB1, specW2,
            defW1, defB1, defW2, defB2, fiPtr, tkPtr, nullptr, out, N);
    }
}